// Round 1
// baseline (57320.111 us; speedup 1.0000x reference)
//
#include <hip/hip_runtime.h>
#include <hip/hip_cooperative_groups.h>
#include <math.h>

namespace cg = cooperative_groups;

struct Ptr8 { const float* p[8]; };

#define Bn 4096
#define Kn 3000
#define KQ4 750          // Kn / 4 (float4s per row)
#define KP 3072          // padded K
#define NSTR 12          // column stripes of 256
#define NCH 40           // row chunks for col reduction
#define GRID_S 480       // NSTR * NCH
#define NW_S (GRID_S * 4)
#define INV_EPS 20.0f
#define INV_TEMP 10.0f
#define TINYF 1e-12f
#define TOLF 1e-3f

__device__ __forceinline__ float wsum(float x) {
#pragma unroll
  for (int o = 32; o; o >>= 1) x += __shfl_xor(x, o, 64);
  return x;
}
__device__ __forceinline__ float wmax(float x) {
#pragma unroll
  for (int o = 32; o; o >>= 1) x = fmaxf(x, __shfl_xor(x, o, 64));
  return x;
}
__device__ __forceinline__ float block_max(float x) {
  __shared__ float s[4];
  x = wmax(x);
  if ((threadIdx.x & 63) == 0) s[threadIdx.x >> 6] = x;
  __syncthreads();
  float r = fmaxf(fmaxf(s[0], s[1]), fmaxf(s[2], s[3]));
  __syncthreads();
  return r;
}

// One full sinkhorn for crops[*idxp]: writes m (rowmax of scores), u, r (=Q@v_final),
// A (row scale), v, C (col scale) so that P_final[b,k] = exp((s-m_b)*20) * A_b * C_k.
__global__ __launch_bounds__(256, 2) void sinkhorn_kernel(
    Ptr8 ptrs, const int* __restrict__ idxp,
    float* __restrict__ ws_m, float* __restrict__ ws_u, float* __restrict__ ws_r,
    float* __restrict__ ws_A, float* __restrict__ ws_v, float* __restrict__ ws_C,
    float* __restrict__ cpart, unsigned* __restrict__ errbuf)
{
  cg::grid_group grid = cg::this_grid();
  const int idx = (*idxp) & 7;
  const float* __restrict__ lg = ptrs.p[idx];
  const int tid = threadIdx.x;
  const int lane = tid & 63;
  const int gw = blockIdx.x * 4 + (tid >> 6);
  const int stripe = blockIdx.x % NSTR;
  const int chunk = blockIdx.x / NSTR;
  const int kcol = stripe * 256 + tid;
  const int rs = (chunk * Bn) / NCH;
  const int re = ((chunk + 1) * Bn) / NCH;
  const float tgt = 4096.0f / 3000.0f;

  // ---- phase 0: row max m_b and r0_b = sum_k exp((s-m)*INV_EPS)  (= Q @ ones)
  for (int row = gw; row < Bn; row += NW_S) {
    const float4* rp = (const float4*)(lg + (size_t)row * Kn);
    float M = -INFINITY, T = 0.f;
    for (int i = lane; i < KQ4; i += 64) {
      float4 x = rp[i];
      float m4 = fmaxf(fmaxf(x.x, x.y), fmaxf(x.z, x.w));
      float t4 = __expf((x.x - m4) * INV_EPS) + __expf((x.y - m4) * INV_EPS)
               + __expf((x.z - m4) * INV_EPS) + __expf((x.w - m4) * INV_EPS);
      float Mn = fmaxf(M, m4);
      T = T * __expf((M - Mn) * INV_EPS) + t4 * __expf((m4 - Mn) * INV_EPS);
      M = Mn;
    }
#pragma unroll
    for (int o = 32; o; o >>= 1) {
      float M2 = __shfl_xor(M, o, 64);
      float T2 = __shfl_xor(T, o, 64);
      float Mn = fmaxf(M, M2);
      T = T * __expf((M - Mn) * INV_EPS) + T2 * __expf((M2 - Mn) * INV_EPS);
      M = Mn;
    }
    if (lane == 0) { ws_m[row] = M; ws_r[row] = T; }
  }
  grid.sync(); __threadfence();

  // ---- sinkhorn loop (faithful to reference while_loop)
  int it = 0;
  while (true) {
    ++it;
    // col pass: partial c_k = sum_{rows in chunk} u_b * Q[b,k], u_b = 1/(r_b+TINY)
    {
      float acc = 0.f;
      if (kcol < Kn) {
        for (int row = rs; row < re; ++row) {
          float u = 1.0f / (ws_r[row] + TINYF);
          acc += u * __expf((lg[(size_t)row * Kn + kcol] - ws_m[row]) * INV_EPS);
        }
      }
      cpart[chunk * KP + stripe * 256 + tid] = acc;
    }
    grid.sync(); __threadfence();
    // v phase: c_k = sum partials; v_k = tgt/(c+TINY); col_err = |v*c - tgt|
    {
      int k = blockIdx.x * 256 + tid;
      float cerr = 0.f;
      if (k < Kn) {
        float c = 0.f;
        for (int ch = 0; ch < NCH; ++ch) c += cpart[ch * KP + k];
        float vk = tgt / (c + TINYF);
        ws_v[k] = vk;
        cerr = fabsf(vk * c - tgt);
      }
      float bm = block_max(cerr);
      if (tid == 0) atomicMax(&errbuf[2 * it + 1], __float_as_uint(bm));
    }
    grid.sync(); __threadfence();
    // row pass: r_new = Q @ v ; row_err = |u * r_new - 1| ; store u
    {
      float lerr = 0.f;
      for (int row = gw; row < Bn; row += NW_S) {
        const float4* rp = (const float4*)(lg + (size_t)row * Kn);
        const float4* vp = (const float4*)ws_v;
        float mm = ws_m[row];
        float u = 1.0f / (ws_r[row] + TINYF);
        float Ssum = 0.f;
        for (int i = lane; i < KQ4; i += 64) {
          float4 x = rp[i];
          float4 vv = vp[i];
          Ssum += __expf((x.x - mm) * INV_EPS) * vv.x
                + __expf((x.y - mm) * INV_EPS) * vv.y
                + __expf((x.z - mm) * INV_EPS) * vv.z
                + __expf((x.w - mm) * INV_EPS) * vv.w;
        }
        Ssum = wsum(Ssum);
        if (lane == 0) { ws_u[row] = u; ws_r[row] = Ssum; }
        lerr = fmaxf(lerr, fabsf(u * Ssum - 1.0f));
      }
      float bm = block_max(lerr);
      if (tid == 0) atomicMax(&errbuf[2 * it], __float_as_uint(bm));
    }
    grid.sync(); __threadfence();
    unsigned rbits = __hip_atomic_load(&errbuf[2 * it], __ATOMIC_RELAXED, __HIP_MEMORY_SCOPE_AGENT);
    unsigned cbits = __hip_atomic_load(&errbuf[2 * it + 1], __ATOMIC_RELAXED, __HIP_MEMORY_SCOPE_AGENT);
    float err = fmaxf(__uint_as_float(rbits), __uint_as_float(cbits));
    if (it >= 3 && (it >= 100 || err <= TOLF)) break;
  }

  // ---- final normalization: P=u*Q*v; /rowsum; *tgt/colsum; /rowsum  ->  Q*A_b*C_k
  // s'_b = max(u_b * r_b, TINY)  (r holds Q@v_final)
  // col pass for d_k = sum_b (u/s') Q
  {
    float acc = 0.f;
    if (kcol < Kn) {
      for (int row = rs; row < re; ++row) {
        float u = ws_u[row];
        float sp = fmaxf(u * ws_r[row], TINYF);
        acc += (u / sp) * __expf((lg[(size_t)row * Kn + kcol] - ws_m[row]) * INV_EPS);
      }
    }
    cpart[chunk * KP + stripe * 256 + tid] = acc;
  }
  grid.sync(); __threadfence();
  // C_k = v_k * tgt / max(v_k * d_k, TINY)
  {
    int k = blockIdx.x * 256 + tid;
    if (k < Kn) {
      float d = 0.f;
      for (int ch = 0; ch < NCH; ++ch) d += cpart[ch * KP + k];
      float vk = ws_v[k];
      ws_C[k] = vk * tgt / fmaxf(vk * d, TINYF);
    }
  }
  grid.sync(); __threadfence();
  // row pass: e_b = sum_k Q*C ; w = (u/s')*e ; A_b = (u/s') / max(w, TINY)
  {
    for (int row = gw; row < Bn; row += NW_S) {
      const float4* rp = (const float4*)(lg + (size_t)row * Kn);
      const float4* cp = (const float4*)ws_C;
      float mm = ws_m[row];
      float e = 0.f;
      for (int i = lane; i < KQ4; i += 64) {
        float4 x = rp[i];
        float4 cc = cp[i];
        e += __expf((x.x - mm) * INV_EPS) * cc.x
           + __expf((x.y - mm) * INV_EPS) * cc.y
           + __expf((x.z - mm) * INV_EPS) * cc.z
           + __expf((x.w - mm) * INV_EPS) * cc.w;
      }
      e = wsum(e);
      if (lane == 0) {
        float u = ws_u[row];
        float sp = fmaxf(u * ws_r[row], TINYF);
        float us = u / sp;
        float w = us * e;
        ws_A[row] = us / fmaxf(w, TINYF);
      }
    }
  }
}

// Fused loss/entropy/qmax pass: one wave per row, one read of all 8 crops.
__global__ __launch_bounds__(256) void loss_kernel(
    Ptr8 ptrs, const int* __restrict__ iap, const int* __restrict__ ibp,
    const float* __restrict__ wsa, const float* __restrict__ wsb,
    float* __restrict__ out)
{
  const int ia = (*iap) & 7;
  const int ib = (*ibp) & 7;
  const int lane = threadIdx.x & 63;
  const int row = blockIdx.x * 4 + (threadIdx.x >> 6);

  const float ma = wsa[row];
  const float Aa = wsa[3 * Bn + row];
  const float mb = wsb[row];
  const float Ab = wsb[3 * Bn + row];
  const float4* Ca4 = (const float4*)(wsa + 4 * Bn + KP);
  const float4* Cb4 = (const float4*)(wsb + 4 * Bn + KP);
  size_t off = (size_t)row * Kn;
  const float4* X4[8];
#pragma unroll
  for (int c = 0; c < 8; ++c) X4[c] = (const float4*)(ptrs.p[c] + off);
  const float4* xa4 = (const float4*)(ptrs.p[ia] + off);
  const float4* xb4 = (const float4*)(ptrs.p[ib] + off);

  float M[8], S[8], da[8], db[8];
#pragma unroll
  for (int c = 0; c < 8; ++c) { M[c] = -INFINITY; S[c] = 0.f; da[c] = 0.f; db[c] = 0.f; }
  float enta = 0.f, entb = 0.f, ra = 0.f, rb = 0.f, qam = 0.f, qbm = 0.f;

  for (int i = lane; i < KQ4; i += 64) {
    float4 xa = xa4[i], xb = xb4[i];
    float4 ca = Ca4[i], cb = Cb4[i];
    float qa0 = __expf((xa.x - ma) * INV_EPS) * Aa * ca.x;
    float qa1 = __expf((xa.y - ma) * INV_EPS) * Aa * ca.y;
    float qa2 = __expf((xa.z - ma) * INV_EPS) * Aa * ca.z;
    float qa3 = __expf((xa.w - ma) * INV_EPS) * Aa * ca.w;
    float qb0 = __expf((xb.x - mb) * INV_EPS) * Ab * cb.x;
    float qb1 = __expf((xb.y - mb) * INV_EPS) * Ab * cb.y;
    float qb2 = __expf((xb.z - mb) * INV_EPS) * Ab * cb.z;
    float qb3 = __expf((xb.w - mb) * INV_EPS) * Ab * cb.w;
    ra += (qa0 + qa1) + (qa2 + qa3);
    rb += (qb0 + qb1) + (qb2 + qb3);
    enta += qa0 * __logf(qa0 + TINYF) + qa1 * __logf(qa1 + TINYF)
          + qa2 * __logf(qa2 + TINYF) + qa3 * __logf(qa3 + TINYF);
    entb += qb0 * __logf(qb0 + TINYF) + qb1 * __logf(qb1 + TINYF)
          + qb2 * __logf(qb2 + TINYF) + qb3 * __logf(qb3 + TINYF);
    qam = fmaxf(qam, fmaxf(fmaxf(qa0, qa1), fmaxf(qa2, qa3)));
    qbm = fmaxf(qbm, fmaxf(fmaxf(qb0, qb1), fmaxf(qb2, qb3)));
#pragma unroll
    for (int c = 0; c < 8; ++c) {
      float4 x = X4[c][i];
      float y0 = x.x * INV_TEMP, y1 = x.y * INV_TEMP;
      float y2 = x.z * INV_TEMP, y3 = x.w * INV_TEMP;
      float m4 = fmaxf(fmaxf(y0, y1), fmaxf(y2, y3));
      float t4 = __expf(y0 - m4) + __expf(y1 - m4) + __expf(y2 - m4) + __expf(y3 - m4);
      float Mn = fmaxf(M[c], m4);
      S[c] = S[c] * __expf(M[c] - Mn) + t4 * __expf(m4 - Mn);
      M[c] = Mn;
      da[c] += qa0 * x.x + qa1 * x.y + qa2 * x.z + qa3 * x.w;
      db[c] += qb0 * x.x + qb1 * x.y + qb2 * x.z + qb3 * x.w;
    }
  }

#pragma unroll
  for (int c = 0; c < 8; ++c) {
#pragma unroll
    for (int o = 32; o; o >>= 1) {
      float M2 = __shfl_xor(M[c], o, 64);
      float S2 = __shfl_xor(S[c], o, 64);
      float Mn = fmaxf(M[c], M2);
      S[c] = S[c] * __expf(M[c] - Mn) + S2 * __expf(M2 - Mn);
      M[c] = Mn;
    }
    da[c] = wsum(da[c]);
    db[c] = wsum(db[c]);
  }
  enta = wsum(enta); entb = wsum(entb);
  ra = wsum(ra); rb = wsum(rb);
  qam = wmax(qam); qbm = wmax(qbm);

  if (lane == 0) {
    float lsum = 0.f;
    int nt = 0;
#pragma unroll
    for (int c = 0; c < 8; ++c) {
      float L = M[c] + __logf(S[c]);
      if (c != ia) { lsum -= INV_TEMP * da[c] - L * ra; ++nt; }
      if (c != ib) { lsum -= INV_TEMP * db[c] - L * rb; ++nt; }
    }
    atomicAdd(&out[0], lsum / ((float)nt * (float)Bn));
    atomicAdd(&out[1], -0.5f / (float)Bn * (enta + entb));
    atomicAdd(&out[2], 0.5f / (float)Bn * (qam + qbm));
  }
}

extern "C" void kernel_launch(void* const* d_in, const int* in_sizes, int n_in,
                              void* d_out, int out_size, void* d_ws, size_t ws_size,
                              hipStream_t stream)
{
  (void)in_sizes; (void)n_in; (void)out_size; (void)ws_size;
  Ptr8 ptrs;
  for (int c = 0; c < 8; ++c) ptrs.p[c] = (const float*)d_in[c];
  const int* iap = (const int*)d_in[8];
  const int* ibp = (const int*)d_in[9];
  float* ws = (float*)d_ws;
  // layout (floats): per-matrix block = [m(4096) u(4096) r(4096) A(4096) v(3072) C(3072)] = 22528
  float* wsa = ws;
  float* wsb = ws + 22528;
  float* cpart = ws + 45056;                     // NCH*KP = 122880
  unsigned* err_a = (unsigned*)(ws + 167936);    // 256 slots
  unsigned* err_b = err_a + 256;
  float* out = (float*)d_out;

  hipMemsetAsync(ws + 167936, 0, 512 * sizeof(unsigned), stream);
  hipMemsetAsync(d_out, 0, 3 * sizeof(float), stream);

  {
    float* m = wsa;          float* u = wsa + 4096;  float* r = wsa + 8192;
    float* A = wsa + 12288;  float* v = wsa + 16384; float* C = wsa + 19456;
    void* args[] = { (void*)&ptrs, (void*)&iap, (void*)&m, (void*)&u, (void*)&r,
                     (void*)&A, (void*)&v, (void*)&C, (void*)&cpart, (void*)&err_a };
    hipLaunchCooperativeKernel((const void*)sinkhorn_kernel, dim3(GRID_S), dim3(256),
                               (void**)args, 0u, stream);
  }
  {
    float* m = wsb;          float* u = wsb + 4096;  float* r = wsb + 8192;
    float* A = wsb + 12288;  float* v = wsb + 16384; float* C = wsb + 19456;
    void* args[] = { (void*)&ptrs, (void*)&ibp, (void*)&m, (void*)&u, (void*)&r,
                     (void*)&A, (void*)&v, (void*)&C, (void*)&cpart, (void*)&err_b };
    hipLaunchCooperativeKernel((const void*)sinkhorn_kernel, dim3(GRID_S), dim3(256),
                               (void**)args, 0u, stream);
  }
  loss_kernel<<<dim3(Bn / 4), dim3(256), 0, stream>>>(ptrs, iap, ibp, wsa, wsb, out);
}

// Round 2
// 39757.242 us; speedup vs baseline: 1.4418x; 1.4418x over previous
//
#include <hip/hip_runtime.h>
#include <hip/hip_cooperative_groups.h>
#include <math.h>

namespace cg = cooperative_groups;

struct Ptr8 { const float* p[8]; };

#define Bn 4096
#define Kn 3000
#define KQ4 750
#define KP 3072
#define INV_EPS 20.0f
#define INV_TEMP 10.0f
#define TINYF 1e-12f
#define TOLF 1e-3f
#define TGTC (4096.0f/3000.0f)

// sparse config
#define SP_NBLK 512
#define SP_NW (SP_NBLK * 4)
#define CAPR 1024
#define CAPC 1024
#define CUTF 2.0f          // keep entries with s >= rowmax - CUTF  (q >= e^-40)

// dense fallback config (round-0)
#define NSTR 12
#define NCH 40
#define GRID_S 480
#define NW_S (GRID_S * 4)

__device__ __forceinline__ float wsum(float x) {
#pragma unroll
  for (int o = 32; o; o >>= 1) x += __shfl_xor(x, o, 64);
  return x;
}
__device__ __forceinline__ float wmax(float x) {
#pragma unroll
  for (int o = 32; o; o >>= 1) x = fmaxf(x, __shfl_xor(x, o, 64));
  return x;
}
__device__ __forceinline__ float block_max(float x) {
  __shared__ float s[4];
  x = wmax(x);
  if ((threadIdx.x & 63) == 0) s[threadIdx.x >> 6] = x;
  __syncthreads();
  float r = fmaxf(fmaxf(s[0], s[1]), fmaxf(s[2], s[3]));
  __syncthreads();
  return r;
}

// ---------------------------------------------------------------------------
// Sparse sinkhorn: persist layout per crop = [m(4096) | A(4096) | C(3072)]
// ---------------------------------------------------------------------------
struct SkArgs {
  Ptr8 ptrs;
  const int* idxp;
  float* pm; float* pA; float* pC;          // persist
  float* u; float* r; float* v; float* alpha;
  unsigned* rowcnt; unsigned* colcnt;
  float* csrq; unsigned short* csridx;
  float* cscq; unsigned short* cscidx;
  unsigned* errbuf;
};

__global__ __launch_bounds__(256, 2) void sinkhorn_sparse(SkArgs a) {
  cg::grid_group grid = cg::this_grid();
  const int idx = (*a.idxp) & 7;
  const float* __restrict__ lg = a.ptrs.p[idx];
  const int tid = threadIdx.x;
  const int lane = tid & 63;
  const int wv = blockIdx.x * 4 + (tid >> 6);
  const int gid = blockIdx.x * 256 + tid;

  if (gid < KP) a.colcnt[gid] = 0;

  // ---- phase 0: row max m_b and r0_b = sum_k exp((s-m)*INV_EPS)
  for (int row = wv; row < Bn; row += SP_NW) {
    const float4* rp = (const float4*)(lg + (size_t)row * Kn);
    float M = -INFINITY, T = 0.f;
    for (int i = lane; i < KQ4; i += 64) {
      float4 x = rp[i];
      float m4 = fmaxf(fmaxf(x.x, x.y), fmaxf(x.z, x.w));
      float t4 = __expf((x.x - m4) * INV_EPS) + __expf((x.y - m4) * INV_EPS)
               + __expf((x.z - m4) * INV_EPS) + __expf((x.w - m4) * INV_EPS);
      float Mn = fmaxf(M, m4);
      T = T * __expf((M - Mn) * INV_EPS) + t4 * __expf((m4 - Mn) * INV_EPS);
      M = Mn;
    }
#pragma unroll
    for (int o = 32; o; o >>= 1) {
      float M2 = __shfl_xor(M, o, 64);
      float T2 = __shfl_xor(T, o, 64);
      float Mn = fmaxf(M, M2);
      T = T * __expf((M - Mn) * INV_EPS) + T2 * __expf((M2 - Mn) * INV_EPS);
      M = Mn;
    }
    if (lane == 0) { a.pm[row] = M; a.r[row] = T; }
  }
  __threadfence();
  grid.sync();

  // ---- build CSR + CSC of q = exp((s-m)*20) for s >= m - CUTF
  for (int row = wv; row < Bn; row += SP_NW) {
    const float4* rp = (const float4*)(lg + (size_t)row * Kn);
    float mm = a.pm[row];
    float thr = mm - CUTF;
    int cnt = 0;
    for (int i = lane; i < KQ4; i += 64) {
      float4 x = rp[i];
      cnt += (x.x >= thr) + (x.y >= thr) + (x.z >= thr) + (x.w >= thr);
    }
    int incl = cnt;
#pragma unroll
    for (int o = 1; o < 64; o <<= 1) {
      int t = __shfl_up(incl, o, 64);
      if (lane >= o) incl += t;
    }
    int total = __shfl(incl, 63, 64);
    int p = incl - cnt;
    if (lane == 0) a.rowcnt[row] = (unsigned)min(total, CAPR);
    float* crow = a.csrq + (size_t)row * CAPR;
    unsigned short* cidx = a.csridx + (size_t)row * CAPR;
    for (int i = lane; i < KQ4; i += 64) {
      float4 x = rp[i];
      int k0 = i * 4;
#define EMIT(val, kk)                                                          \
      if ((val) >= thr) {                                                      \
        float q = __expf(((val) - mm) * INV_EPS);                              \
        if (p < CAPR) { crow[p] = q; cidx[p] = (unsigned short)(kk); }         \
        unsigned slot = atomicAdd(&a.colcnt[kk], 1u);                          \
        if (slot < CAPC) {                                                     \
          size_t o2 = (size_t)(kk) * CAPC + slot;                              \
          a.cscq[o2] = q; a.cscidx[o2] = (unsigned short)row;                  \
        }                                                                      \
        ++p;                                                                   \
      }
      EMIT(x.x, k0 + 0) EMIT(x.y, k0 + 1) EMIT(x.z, k0 + 2) EMIT(x.w, k0 + 3)
#undef EMIT
    }
  }
  __threadfence();
  grid.sync();

  // ---- sinkhorn loop on sparse data
  int it = 0;
  while (true) {
    ++it;
    // col pass: c_k = sum q * u_row, u = 1/(r+TINY); fuse v update
    float cerr = 0.f;
    for (int col = wv; col < Kn; col += SP_NW) {
      const float* cq = a.cscq + (size_t)col * CAPC;
      const unsigned short* ci = a.cscidx + (size_t)col * CAPC;
      int n = min((int)a.colcnt[col], CAPC);
      float acc = 0.f;
      for (int j = lane; j < n; j += 64) {
        float rr = a.r[ci[j]];
        acc += cq[j] / (rr + TINYF);
      }
      acc = wsum(acc);
      float vk = TGTC / (acc + TINYF);
      if (lane == 0) a.v[col] = vk;
      cerr = fmaxf(cerr, fabsf(vk * acc - TGTC));
    }
    {
      float bm = block_max(cerr);
      if (tid == 0) atomicMax(&a.errbuf[2 * it + 1], __float_as_uint(bm));
    }
    __threadfence();
    grid.sync();
    // row pass: r_new = Q @ v ; err ; store u used this iter
    float lerr = 0.f;
    for (int row = wv; row < Bn; row += SP_NW) {
      const float* rq = a.csrq + (size_t)row * CAPR;
      const unsigned short* ri = a.csridx + (size_t)row * CAPR;
      int n = min((int)a.rowcnt[row], CAPR);
      float acc = 0.f;
      for (int j = lane; j < n; j += 64) acc += rq[j] * a.v[ri[j]];
      acc = wsum(acc);
      float uu = 1.0f / (a.r[row] + TINYF);
      if (lane == 0) { a.u[row] = uu; a.r[row] = acc; }
      lerr = fmaxf(lerr, fabsf(uu * acc - 1.0f));
    }
    {
      float bm = block_max(lerr);
      if (tid == 0) atomicMax(&a.errbuf[2 * it], __float_as_uint(bm));
    }
    __threadfence();
    grid.sync();
    unsigned rbits = __hip_atomic_load(&a.errbuf[2 * it], __ATOMIC_RELAXED, __HIP_MEMORY_SCOPE_AGENT);
    unsigned cbits = __hip_atomic_load(&a.errbuf[2 * it + 1], __ATOMIC_RELAXED, __HIP_MEMORY_SCOPE_AGENT);
    float err = fmaxf(__uint_as_float(rbits), __uint_as_float(cbits));
    if (it >= 3 && (it >= 100 || err <= TOLF)) break;
  }

  // ---- final normalization -> A_b, C_k  (P = q * A_b * C_k)
  if (gid < Bn) {
    float uu = a.u[gid], rr = a.r[gid];
    a.alpha[gid] = uu / fmaxf(uu * rr, TINYF);
  }
  __threadfence();
  grid.sync();
  for (int col = wv; col < Kn; col += SP_NW) {
    const float* cq = a.cscq + (size_t)col * CAPC;
    const unsigned short* ci = a.cscidx + (size_t)col * CAPC;
    int n = min((int)a.colcnt[col], CAPC);
    float d = 0.f;
    for (int j = lane; j < n; j += 64) d += cq[j] * a.alpha[ci[j]];
    d = wsum(d);
    float vk = a.v[col];
    if (lane == 0) a.pC[col] = vk * TGTC / fmaxf(vk * d, TINYF);
  }
  __threadfence();
  grid.sync();
  for (int row = wv; row < Bn; row += SP_NW) {
    const float* rq = a.csrq + (size_t)row * CAPR;
    const unsigned short* ri = a.csridx + (size_t)row * CAPR;
    int n = min((int)a.rowcnt[row], CAPR);
    float e = 0.f;
    for (int j = lane; j < n; j += 64) e += rq[j] * a.pC[ri[j]];
    e = wsum(e);
    if (lane == 0) {
      float al = a.alpha[row];
      a.pA[row] = al / fmaxf(al * e, TINYF);
    }
  }
}

// ---------------------------------------------------------------------------
// Dense fallback (round-0 kernel), used only if ws_size is too small.
// Writes persist layout m/A/C like the sparse kernel.
// ---------------------------------------------------------------------------
__global__ __launch_bounds__(256, 2) void sinkhorn_dense(
    Ptr8 ptrs, const int* __restrict__ idxp,
    float* __restrict__ ws_m, float* __restrict__ ws_u, float* __restrict__ ws_r,
    float* __restrict__ ws_A, float* __restrict__ ws_v, float* __restrict__ ws_C,
    float* __restrict__ cpart, unsigned* __restrict__ errbuf)
{
  cg::grid_group grid = cg::this_grid();
  const int idx = (*idxp) & 7;
  const float* __restrict__ lg = ptrs.p[idx];
  const int tid = threadIdx.x;
  const int lane = tid & 63;
  const int gw = blockIdx.x * 4 + (tid >> 6);
  const int stripe = blockIdx.x % NSTR;
  const int chunk = blockIdx.x / NSTR;
  const int kcol = stripe * 256 + tid;
  const int rs = (chunk * Bn) / NCH;
  const int re = ((chunk + 1) * Bn) / NCH;

  for (int row = gw; row < Bn; row += NW_S) {
    const float4* rp = (const float4*)(lg + (size_t)row * Kn);
    float M = -INFINITY, T = 0.f;
    for (int i = lane; i < KQ4; i += 64) {
      float4 x = rp[i];
      float m4 = fmaxf(fmaxf(x.x, x.y), fmaxf(x.z, x.w));
      float t4 = __expf((x.x - m4) * INV_EPS) + __expf((x.y - m4) * INV_EPS)
               + __expf((x.z - m4) * INV_EPS) + __expf((x.w - m4) * INV_EPS);
      float Mn = fmaxf(M, m4);
      T = T * __expf((M - Mn) * INV_EPS) + t4 * __expf((m4 - Mn) * INV_EPS);
      M = Mn;
    }
#pragma unroll
    for (int o = 32; o; o >>= 1) {
      float M2 = __shfl_xor(M, o, 64);
      float T2 = __shfl_xor(T, o, 64);
      float Mn = fmaxf(M, M2);
      T = T * __expf((M - Mn) * INV_EPS) + T2 * __expf((M2 - Mn) * INV_EPS);
      M = Mn;
    }
    if (lane == 0) { ws_m[row] = M; ws_r[row] = T; }
  }
  grid.sync(); __threadfence();

  int it = 0;
  while (true) {
    ++it;
    {
      float acc = 0.f;
      if (kcol < Kn) {
        for (int row = rs; row < re; ++row) {
          float u = 1.0f / (ws_r[row] + TINYF);
          acc += u * __expf((lg[(size_t)row * Kn + kcol] - ws_m[row]) * INV_EPS);
        }
      }
      cpart[chunk * KP + stripe * 256 + tid] = acc;
    }
    grid.sync(); __threadfence();
    {
      int k = blockIdx.x * 256 + tid;
      float cerr = 0.f;
      if (k < Kn) {
        float c = 0.f;
        for (int ch = 0; ch < NCH; ++ch) c += cpart[ch * KP + k];
        float vk = TGTC / (c + TINYF);
        ws_v[k] = vk;
        cerr = fabsf(vk * c - TGTC);
      }
      float bm = block_max(cerr);
      if (tid == 0) atomicMax(&errbuf[2 * it + 1], __float_as_uint(bm));
    }
    grid.sync(); __threadfence();
    {
      float lerr = 0.f;
      for (int row = gw; row < Bn; row += NW_S) {
        const float4* rp = (const float4*)(lg + (size_t)row * Kn);
        const float4* vp = (const float4*)ws_v;
        float mm = ws_m[row];
        float u = 1.0f / (ws_r[row] + TINYF);
        float Ssum = 0.f;
        for (int i = lane; i < KQ4; i += 64) {
          float4 x = rp[i];
          float4 vv = vp[i];
          Ssum += __expf((x.x - mm) * INV_EPS) * vv.x
                + __expf((x.y - mm) * INV_EPS) * vv.y
                + __expf((x.z - mm) * INV_EPS) * vv.z
                + __expf((x.w - mm) * INV_EPS) * vv.w;
        }
        Ssum = wsum(Ssum);
        if (lane == 0) { ws_u[row] = u; ws_r[row] = Ssum; }
        lerr = fmaxf(lerr, fabsf(u * Ssum - 1.0f));
      }
      float bm = block_max(lerr);
      if (tid == 0) atomicMax(&errbuf[2 * it], __float_as_uint(bm));
    }
    grid.sync(); __threadfence();
    unsigned rbits = __hip_atomic_load(&errbuf[2 * it], __ATOMIC_RELAXED, __HIP_MEMORY_SCOPE_AGENT);
    unsigned cbits = __hip_atomic_load(&errbuf[2 * it + 1], __ATOMIC_RELAXED, __HIP_MEMORY_SCOPE_AGENT);
    float err = fmaxf(__uint_as_float(rbits), __uint_as_float(cbits));
    if (it >= 3 && (it >= 100 || err <= TOLF)) break;
  }

  {
    float acc = 0.f;
    if (kcol < Kn) {
      for (int row = rs; row < re; ++row) {
        float u = ws_u[row];
        float sp = fmaxf(u * ws_r[row], TINYF);
        acc += (u / sp) * __expf((lg[(size_t)row * Kn + kcol] - ws_m[row]) * INV_EPS);
      }
    }
    cpart[chunk * KP + stripe * 256 + tid] = acc;
  }
  grid.sync(); __threadfence();
  {
    int k = blockIdx.x * 256 + tid;
    if (k < Kn) {
      float d = 0.f;
      for (int ch = 0; ch < NCH; ++ch) d += cpart[ch * KP + k];
      float vk = ws_v[k];
      ws_C[k] = vk * TGTC / fmaxf(vk * d, TINYF);
    }
  }
  grid.sync(); __threadfence();
  {
    for (int row = gw; row < Bn; row += NW_S) {
      const float4* rp = (const float4*)(lg + (size_t)row * Kn);
      const float4* cp = (const float4*)ws_C;
      float mm = ws_m[row];
      float e = 0.f;
      for (int i = lane; i < KQ4; i += 64) {
        float4 x = rp[i];
        float4 cc = cp[i];
        e += __expf((x.x - mm) * INV_EPS) * cc.x
           + __expf((x.y - mm) * INV_EPS) * cc.y
           + __expf((x.z - mm) * INV_EPS) * cc.z
           + __expf((x.w - mm) * INV_EPS) * cc.w;
      }
      e = wsum(e);
      if (lane == 0) {
        float u = ws_u[row];
        float sp = fmaxf(u * ws_r[row], TINYF);
        float us = u / sp;
        float w = us * e;
        ws_A[row] = us / fmaxf(w, TINYF);
      }
    }
  }
}

// ---------------------------------------------------------------------------
// Fused loss/entropy/qmax pass (persist layout: m@0, A@4096, C@8192)
// ---------------------------------------------------------------------------
__global__ __launch_bounds__(256) void loss_kernel(
    Ptr8 ptrs, const int* __restrict__ iap, const int* __restrict__ ibp,
    const float* __restrict__ wsa, const float* __restrict__ wsb,
    float* __restrict__ out)
{
  const int ia = (*iap) & 7;
  const int ib = (*ibp) & 7;
  const int lane = threadIdx.x & 63;
  const int row = blockIdx.x * 4 + (threadIdx.x >> 6);

  const float ma = wsa[row];
  const float Aa = wsa[4096 + row];
  const float mb = wsb[row];
  const float Ab = wsb[4096 + row];
  const float4* Ca4 = (const float4*)(wsa + 8192);
  const float4* Cb4 = (const float4*)(wsb + 8192);
  size_t off = (size_t)row * Kn;
  const float4* X4[8];
#pragma unroll
  for (int c = 0; c < 8; ++c) X4[c] = (const float4*)(ptrs.p[c] + off);
  const float4* xa4 = (const float4*)(ptrs.p[ia] + off);
  const float4* xb4 = (const float4*)(ptrs.p[ib] + off);

  float M[8], S[8], da[8], db[8];
#pragma unroll
  for (int c = 0; c < 8; ++c) { M[c] = -INFINITY; S[c] = 0.f; da[c] = 0.f; db[c] = 0.f; }
  float enta = 0.f, entb = 0.f, ra = 0.f, rb = 0.f, qam = 0.f, qbm = 0.f;

  for (int i = lane; i < KQ4; i += 64) {
    float4 xa = xa4[i], xb = xb4[i];
    float4 ca = Ca4[i], cb = Cb4[i];
    float qa0 = __expf((xa.x - ma) * INV_EPS) * Aa * ca.x;
    float qa1 = __expf((xa.y - ma) * INV_EPS) * Aa * ca.y;
    float qa2 = __expf((xa.z - ma) * INV_EPS) * Aa * ca.z;
    float qa3 = __expf((xa.w - ma) * INV_EPS) * Aa * ca.w;
    float qb0 = __expf((xb.x - mb) * INV_EPS) * Ab * cb.x;
    float qb1 = __expf((xb.y - mb) * INV_EPS) * Ab * cb.y;
    float qb2 = __expf((xb.z - mb) * INV_EPS) * Ab * cb.z;
    float qb3 = __expf((xb.w - mb) * INV_EPS) * Ab * cb.w;
    ra += (qa0 + qa1) + (qa2 + qa3);
    rb += (qb0 + qb1) + (qb2 + qb3);
    enta += qa0 * __logf(qa0 + TINYF) + qa1 * __logf(qa1 + TINYF)
          + qa2 * __logf(qa2 + TINYF) + qa3 * __logf(qa3 + TINYF);
    entb += qb0 * __logf(qb0 + TINYF) + qb1 * __logf(qb1 + TINYF)
          + qb2 * __logf(qb2 + TINYF) + qb3 * __logf(qb3 + TINYF);
    qam = fmaxf(qam, fmaxf(fmaxf(qa0, qa1), fmaxf(qa2, qa3)));
    qbm = fmaxf(qbm, fmaxf(fmaxf(qb0, qb1), fmaxf(qb2, qb3)));
#pragma unroll
    for (int c = 0; c < 8; ++c) {
      float4 x = X4[c][i];
      float y0 = x.x * INV_TEMP, y1 = x.y * INV_TEMP;
      float y2 = x.z * INV_TEMP, y3 = x.w * INV_TEMP;
      float m4 = fmaxf(fmaxf(y0, y1), fmaxf(y2, y3));
      float t4 = __expf(y0 - m4) + __expf(y1 - m4) + __expf(y2 - m4) + __expf(y3 - m4);
      float Mn = fmaxf(M[c], m4);
      S[c] = S[c] * __expf(M[c] - Mn) + t4 * __expf(m4 - Mn);
      M[c] = Mn;
      da[c] += qa0 * x.x + qa1 * x.y + qa2 * x.z + qa3 * x.w;
      db[c] += qb0 * x.x + qb1 * x.y + qb2 * x.z + qb3 * x.w;
    }
  }

#pragma unroll
  for (int c = 0; c < 8; ++c) {
#pragma unroll
    for (int o = 32; o; o >>= 1) {
      float M2 = __shfl_xor(M[c], o, 64);
      float S2 = __shfl_xor(S[c], o, 64);
      float Mn = fmaxf(M[c], M2);
      S[c] = S[c] * __expf(M[c] - Mn) + S2 * __expf(M2 - Mn);
      M[c] = Mn;
    }
    da[c] = wsum(da[c]);
    db[c] = wsum(db[c]);
  }
  enta = wsum(enta); entb = wsum(entb);
  ra = wsum(ra); rb = wsum(rb);
  qam = wmax(qam); qbm = wmax(qbm);

  if (lane == 0) {
    float lsum = 0.f;
    int nt = 0;
#pragma unroll
    for (int c = 0; c < 8; ++c) {
      float L = M[c] + __logf(S[c]);
      if (c != ia) { lsum -= INV_TEMP * da[c] - L * ra; ++nt; }
      if (c != ib) { lsum -= INV_TEMP * db[c] - L * rb; ++nt; }
    }
    atomicAdd(&out[0], lsum / ((float)nt * (float)Bn));
    atomicAdd(&out[1], -0.5f / (float)Bn * (enta + entb));
    atomicAdd(&out[2], 0.5f / (float)Bn * (qam + qbm));
  }
}

// ---------------------------------------------------------------------------
extern "C" void kernel_launch(void* const* d_in, const int* in_sizes, int n_in,
                              void* d_out, int out_size, void* d_ws, size_t ws_size,
                              hipStream_t stream)
{
  (void)in_sizes; (void)n_in; (void)out_size;
  Ptr8 ptrs;
  for (int c = 0; c < 8; ++c) ptrs.p[c] = (const float*)d_in[c];
  const int* iap = (const int*)d_in[8];
  const int* ibp = (const int*)d_in[9];
  float* ws = (float*)d_ws;
  float* out = (float*)d_out;

  // float-offset layout
  float* PA = ws;                 // m,A,C persist crop a (11264)
  float* PB = ws + 11264;         // persist crop b
  float* u_ = ws + 22528;
  float* r_ = ws + 26624;
  float* v_ = ws + 30720;
  float* al = ws + 33792;
  unsigned* rowcnt = (unsigned*)(ws + 37888);
  unsigned* colcnt = (unsigned*)(ws + 41984);
  unsigned* errA = (unsigned*)(ws + 45056);
  unsigned* errB = (unsigned*)(ws + 45568);
  float* csrq = ws + 46080;                                   // 4096*1024
  unsigned short* csridx = (unsigned short*)(ws + 4240384);   // 4096*1024 u16
  float* cscq = ws + 6337536;                                 // 3072*1024
  unsigned short* cscidx = (unsigned short*)(ws + 9483264);   // 3072*1024 u16
  const size_t need_bytes = (size_t)11056128 * 4;

  hipMemsetAsync(errA, 0, 1024 * sizeof(unsigned), stream);
  hipMemsetAsync(d_out, 0, 3 * sizeof(float), stream);

  if (ws_size >= need_bytes) {
    SkArgs sa;
    sa.ptrs = ptrs; sa.idxp = iap;
    sa.pm = PA; sa.pA = PA + 4096; sa.pC = PA + 8192;
    sa.u = u_; sa.r = r_; sa.v = v_; sa.alpha = al;
    sa.rowcnt = rowcnt; sa.colcnt = colcnt;
    sa.csrq = csrq; sa.csridx = csridx; sa.cscq = cscq; sa.cscidx = cscidx;
    sa.errbuf = errA;
    void* args1[] = { (void*)&sa };
    hipLaunchCooperativeKernel((const void*)sinkhorn_sparse, dim3(SP_NBLK), dim3(256),
                               (void**)args1, 0u, stream);
    SkArgs sb = sa;
    sb.idxp = ibp;
    sb.pm = PB; sb.pA = PB + 4096; sb.pC = PB + 8192;
    sb.errbuf = errB;
    void* args2[] = { (void*)&sb };
    hipLaunchCooperativeKernel((const void*)sinkhorn_sparse, dim3(SP_NBLK), dim3(256),
                               (void**)args2, 0u, stream);
  } else {
    // dense fallback (round-0 path); cpart reuses the csrq region start
    float* cpart = ws + 46080;   // NCH*KP = 122880 floats
    {
      float* m = PA; float* A = PA + 4096; float* C = PA + 8192;
      void* args[] = { (void*)&ptrs, (void*)&iap, (void*)&m, (void*)&u_, (void*)&r_,
                       (void*)&A, (void*)&v_, (void*)&C, (void*)&cpart, (void*)&errA };
      hipLaunchCooperativeKernel((const void*)sinkhorn_dense, dim3(GRID_S), dim3(256),
                                 (void**)args, 0u, stream);
    }
    {
      float* m = PB; float* A = PB + 4096; float* C = PB + 8192;
      void* args[] = { (void*)&ptrs, (void*)&ibp, (void*)&m, (void*)&u_, (void*)&r_,
                       (void*)&A, (void*)&v_, (void*)&C, (void*)&cpart, (void*)&errB };
      hipLaunchCooperativeKernel((const void*)sinkhorn_dense, dim3(GRID_S), dim3(256),
                                 (void**)args, 0u, stream);
    }
  }

  loss_kernel<<<dim3(Bn / 4), dim3(256), 0, stream>>>(ptrs, iap, ibp, PA, PB, out);
}